// Round 4
// baseline (2432.702 us; speedup 1.0000x reference)
//
#include <hip/hip_runtime.h>
#include <hip/hip_bf16.h>
#include <math.h>

#ifndef M_PI
#define M_PI 3.14159265358979323846
#endif

// Problem constants
#define NN 10000      // nodes
#define NE 160000     // edges
#define NC 16         // channels (in = hid = out)
#define NQ 5          // 2*order+1
#define NFR 10        // N_FREQ * N_RINGS = 5*2
#define CQ 80         // NC*NQ
#define OP 80         // NC*NQ outputs per node
#define WSZ 64000     // NC*NC*NQ*NQ*NFR

// ---------------------------------------------------------------------------
// Reorder W[o,c,p,q,f,r] -> Wr[fr][cq][op]   (fr=f*2+r, cq=c*5+q, op=o*5+p)
// ---------------------------------------------------------------------------
__global__ void reorder_w(const float* __restrict__ W1, const float* __restrict__ W2,
                          float* __restrict__ Wr1, float* __restrict__ Wr2) {
    int i = blockIdx.x * blockDim.x + threadIdx.x;
    if (i >= WSZ) return;
    int fr = i / 6400;
    int rem = i % 6400;
    int cq = rem / OP;
    int op = rem % OP;
    int c = cq / NQ, q = cq % NQ;
    int o = op / NQ, p = op % NQ;
    int f = fr / 2, r = fr % 2;
    int src = ((((o * NC + c) * NQ + p) * NQ + q) * 5 + f) * 2 + r;
    Wr1[i] = W1[src];
    Wr2[i] = W2[src];
}

// ---------------------------------------------------------------------------
// Self-interaction + bias: y[n,op] = sum_{cq} x[n,cq] * Ws[o,c,p,q] + (p==0)*b[o]
// Writes y fully (serves as the init before edge atomics).
// ---------------------------------------------------------------------------
__global__ void selfint(const float* __restrict__ xin, const float* __restrict__ Ws,
                        const float* __restrict__ b, float* __restrict__ y) {
    __shared__ float ws_s[NC * NC * NQ * NQ];  // 6400 floats = 25.6 KB
    int tid = threadIdx.x;
    for (int i = tid; i < NC * NC * NQ * NQ; i += blockDim.x) ws_s[i] = Ws[i];
    __syncthreads();
    int idx = blockIdx.x * blockDim.x + tid;     // over N*80 = 800000
    if (idx >= NN * OP) return;
    int n = idx / OP, op = idx % OP;
    int o = op / NQ, p = op % NQ;
    const float* xrow = xin + n * CQ;
    float acc = (p == 0) ? b[o] : 0.0f;
    #pragma unroll
    for (int c = 0; c < NC; ++c) {
        #pragma unroll
        for (int q = 0; q < NQ; ++q) {
            acc = fmaf(xrow[c * NQ + q], ws_s[o * 400 + c * 25 + p * 5 + q], acc);
        }
    }
    y[idx] = acc;
}

// ---------------------------------------------------------------------------
// Edge conv v3: one lane per edge, 256-thread blocks (NE = 625 * 256 exactly).
// fr outermost; W[fr] slice (6400 floats = 25.6 KB) staged in LDS per block,
// read via broadcast. launch_bounds(256,2): R3's (256,4) made the allocator
// spill acc[80] to scratch (VGPR_Count=64, +260MB scratch writes/dispatch,
// VALUBusy 14%). Budget 256 VGPRs -> ~115 used -> 4 waves/SIMD, no spill.
// ---------------------------------------------------------------------------
__global__ __launch_bounds__(256, 2)
void edge_conv(const float* __restrict__ xin, const int* __restrict__ ei,
               const float* __restrict__ pre, const float* __restrict__ phi_arr,
               const float* __restrict__ Wr, float* __restrict__ y) {
    __shared__ float w_s[6400];   // 25.6 KB
    const int tid = threadIdx.x;
    const int e = blockIdx.x * 256 + tid;   // exact fit: no guard, no early return

    const int src = ei[2 * e];
    const int dst = ei[2 * e + 1];
    float s1, c1;
    sincosf(phi_arr[e], &s1, &c1);
    const float c2 = c1 * c1 - s1 * s1;
    const float s2 = 2.0f * c1 * s1;

    float acc[OP];
    #pragma unroll
    for (int j = 0; j < OP; ++j) acc[j] = 0.0f;

    const float* xrow = xin + (size_t)src * CQ;
    const float4* wsrc = (const float4*)Wr;

    for (int fr = 0; fr < NFR; ++fr) {
        __syncthreads();   // protect previous iteration's w_s reads
        // Cooperative stage of W[fr]: 1600 float4s across 256 threads
        for (int i = tid; i < 1600; i += 256) {
            ((float4*)w_s)[i] = wsrc[fr * 1600 + i];
        }
        __syncthreads();

        const float tf = pre[e * NFR + fr];  // coalesced, L1/L2-hot after fr=0

        #pragma unroll 1
        for (int c = 0; c < NC; ++c) {
            const float a0  = xrow[c * NQ + 0];
            const float a1  = xrow[c * NQ + 1];
            const float b1v = xrow[c * NQ + 2];
            const float a2  = xrow[c * NQ + 3];
            const float b2v = xrow[c * NQ + 4];
            float u[NQ];
            u[0] = a0 * tf;
            u[1] = (c1 * a1 - s1 * b1v) * tf;
            u[2] = (s1 * a1 + c1 * b1v) * tf;
            u[3] = (c2 * a2 - s2 * b2v) * tf;
            u[4] = (s2 * a2 + c2 * b2v) * tf;
            const float* __restrict__ wb = w_s + c * NQ * OP;
            #pragma unroll
            for (int q = 0; q < NQ; ++q) {
                #pragma unroll
                for (int op = 0; op < OP; ++op) {
                    acc[op] = fmaf(u[q], wb[q * OP + op], acc[op]);
                }
            }
        }
    }

    float* yd = y + (size_t)dst * OP;
    #pragma unroll
    for (int op = 0; op < OP; ++op) atomicAdd(yd + op, acc[op]);
}

// ---------------------------------------------------------------------------
// Regular nonlinearity (Fourier -> 7 samples -> ReLU -> Fourier), optional
// residual add on the input coefficients. One thread per (n,c).
// ---------------------------------------------------------------------------
__global__ void nonlin(const float* __restrict__ yin, const float* __restrict__ res,
                       float* __restrict__ out) {
    int idx = blockIdx.x * blockDim.x + threadIdx.x;  // over N*C = 160000
    if (idx >= NN * NC) return;
    const float* vp = yin + (long long)idx * NQ;
    float a0 = vp[0], a1 = vp[1], a2 = vp[2], a3 = vp[3], a4 = vp[4];
    if (res != nullptr) {
        const float* rp = res + (long long)idx * NQ;
        a0 += rp[0]; a1 += rp[1]; a2 += rp[2]; a3 += rp[3]; a4 += rp[4];
    }
    float o0 = 0.f, o1 = 0.f, o2 = 0.f, o3 = 0.f, o4 = 0.f;
    #pragma unroll
    for (int k = 0; k < 7; ++k) {
        float th = (float)(2.0 * M_PI / 7.0) * (float)k;
        float c1k = cosf(th), s1k = sinf(th);
        float c2k = cosf(2.0f * th), s2k = sinf(2.0f * th);
        float s = a0 + a1 * c1k + a2 * s1k + a3 * c2k + a4 * s2k;
        s = fmaxf(s, 0.0f);
        o0 += s;
        o1 += s * c1k; o2 += s * s1k;
        o3 += s * c2k; o4 += s * s2k;
    }
    const float i7 = 1.0f / 7.0f, t7 = 2.0f / 7.0f;
    float* op = out + (long long)idx * NQ;
    op[0] = o0 * i7;
    op[1] = o1 * t7; op[2] = o2 * t7;
    op[3] = o3 * t7; op[4] = o4 * t7;
}

// ---------------------------------------------------------------------------
extern "C" void kernel_launch(void* const* d_in, const int* in_sizes, int n_in,
                              void* d_out, int out_size, void* d_ws, size_t ws_size,
                              hipStream_t stream) {
    const float* x    = (const float*)d_in[0];
    const int*   ei   = (const int*)d_in[1];      // int inputs arrive as int32
    const float* pre  = (const float*)d_in[2];
    const float* phi  = (const float*)d_in[3];
    const float* W1   = (const float*)d_in[4];
    const float* b1   = (const float*)d_in[5];
    const float* Ws1  = (const float*)d_in[6];
    const float* W2   = (const float*)d_in[7];
    const float* b2   = (const float*)d_in[8];
    const float* Ws2  = (const float*)d_in[9];
    float* out = (float*)d_out;

    // Workspace layout (floats)
    float* ws   = (float*)d_ws;
    float* Wr1  = ws;                     // 64000
    float* Wr2  = Wr1 + WSZ;              // 64000
    float* y1   = Wr2 + WSZ;              // 800000  (also reused as y2)
    float* h    = y1 + (size_t)NN * OP;   // 800000
    // total: 1,728,000 floats = 6.9 MB

    reorder_w<<<(WSZ + 255) / 256, 256, 0, stream>>>(W1, W2, Wr1, Wr2);

    // Layer 1
    selfint<<<(NN * OP + 255) / 256, 256, 0, stream>>>(x, Ws1, b1, y1);
    edge_conv<<<NE / 256, 256, 0, stream>>>(x, ei, pre, phi, Wr1, y1);
    nonlin<<<(NN * NC + 255) / 256, 256, 0, stream>>>(y1, nullptr, h);

    // Layer 2 (reuse y1 buffer as y2)
    selfint<<<(NN * OP + 255) / 256, 256, 0, stream>>>(h, Ws2, b2, y1);
    edge_conv<<<NE / 256, 256, 0, stream>>>(h, ei, pre, phi, Wr2, y1);

    // Residual + final nonlinearity -> d_out
    nonlin<<<(NN * NC + 255) / 256, 256, 0, stream>>>(y1, x, out);
}

// Round 5
// 340.229 us; speedup vs baseline: 7.1502x; 7.1502x over previous
//
#include <hip/hip_runtime.h>
#include <hip/hip_bf16.h>
#include <math.h>

#ifndef M_PI
#define M_PI 3.14159265358979323846
#endif

// Problem constants
#define NN 10000      // nodes
#define NE 160000     // edges
#define NC 16         // channels
#define NQ 5          // 2*order+1
#define NFR 10        // N_FREQ * N_RINGS
#define CQ 80         // NC*NQ (K per fr)
#define OP 80         // outputs per node
#define KTOT 800      // NFR*CQ — GEMM K
#define WSZ 64000     // 80*800 weight elements

#define MT 32         // edges per block in edge GEMM
#define AS_STRIDE 808 // A_s row stride in shorts (800 + 8 pad; 1616 B = 101*16)

typedef __attribute__((ext_vector_type(8))) short bf16x8;
typedef __attribute__((ext_vector_type(4))) float f32x4;

// exact RNE float->bf16 (finite inputs)
static __device__ __forceinline__ unsigned short f2bf(float f) {
    unsigned u = __float_as_uint(f);
    unsigned r = (u + 0x7fffu + ((u >> 16) & 1u)) >> 16;
    return (unsigned short)r;
}

// ---------------------------------------------------------------------------
// Reorder + convert: W[o,c,p,q,f,r] fp32 -> Wt[n=o*5+p][k=(f*2+r)*80+c*5+q] bf16
// (B-operand layout: n-major, k-contiguous -> one dwordx4 per B fragment)
// ---------------------------------------------------------------------------
__global__ void reorder_wt(const float* __restrict__ W1, const float* __restrict__ W2,
                           unsigned short* __restrict__ Wt1, unsigned short* __restrict__ Wt2) {
    int i = blockIdx.x * blockDim.x + threadIdx.x;  // over 64000
    if (i >= WSZ) return;
    int n = i / KTOT;
    int k = i % KTOT;
    int o = n / NQ, p = n % NQ;
    int fr = k / CQ, cq = k % CQ;
    int c = cq / NQ, q = cq % NQ;
    int f = fr / 2, r = fr % 2;
    int src = ((((o * NC + c) * NQ + p) * NQ + q) * 5 + f) * 2 + r;
    Wt1[i] = f2bf(W1[src]);
    Wt2[i] = f2bf(W2[src]);
}

// ---------------------------------------------------------------------------
// Self-interaction + bias (fp32): y[n,op] = sum_cq x[n,cq]*Ws[o,c,p,q] + (p==0)b[o]
// Full write — serves as init before edge atomics.
// ---------------------------------------------------------------------------
__global__ void selfint(const float* __restrict__ xin, const float* __restrict__ Ws,
                        const float* __restrict__ b, float* __restrict__ y) {
    __shared__ float ws_s[NC * NC * NQ * NQ];  // 25.6 KB
    int tid = threadIdx.x;
    for (int i = tid; i < NC * NC * NQ * NQ; i += blockDim.x) ws_s[i] = Ws[i];
    __syncthreads();
    int idx = blockIdx.x * blockDim.x + tid;     // over N*80
    if (idx >= NN * OP) return;
    int n = idx / OP, op = idx % OP;
    int o = op / NQ, p = op % NQ;
    const float* xrow = xin + n * CQ;
    float acc = (p == 0) ? b[o] : 0.0f;
    #pragma unroll
    for (int c = 0; c < NC; ++c)
        #pragma unroll
        for (int q = 0; q < NQ; ++q)
            acc = fmaf(xrow[c * NQ + q], ws_s[o * 400 + c * 25 + p * 5 + q], acc);
    y[idx] = acc;
}

// ---------------------------------------------------------------------------
// Edge conv as MFMA GEMM. Block = 128 threads (2 waves), 32 edges.
// Phase 1 (build): 4 threads/edge gather x[src] (20 floats each), transport,
//   scale by t[e,fr], pack bf16 into A_s[32][800] (padded stride).
// Phase 2 (GEMM): wave w -> edge rows 16w..16w+15; 25 K-steps x 5 n-tiles of
//   v_mfma_f32_16x16x32_bf16. A-frag: ds_read_b128; B-frag: global dwordx4
//   from Wt (L2-hot 128 KB).  Verified layouts (m89): A[m=lane&15][k=quad*8+j],
//   B[k=quad*8+j][n=lane&15], C/D col=lane&15 row=quad*4+reg.
// Phase 3: atomic scatter to y[dst].
// ---------------------------------------------------------------------------
__global__ __launch_bounds__(128)
void edge_conv_mfma(const float* __restrict__ xin, const int* __restrict__ ei,
                    const float* __restrict__ pre, const float* __restrict__ phi_arr,
                    const unsigned short* __restrict__ Wt, float* __restrict__ y) {
    __shared__ __align__(16) unsigned short A_s[MT * AS_STRIDE];  // 51,712 B
    __shared__ int dst_s[MT];

    const int tid = threadIdx.x;
    const int e0 = blockIdx.x * MT;     // NE = 5000 * 32 exactly

    // ---- Phase 1: build A tile ----
    const int el = tid >> 2;            // local edge 0..31
    const int q4 = tid & 3;             // cq quarter [20*q4, 20*q4+20)
    const int e  = e0 + el;
    const int src = ei[2 * e];
    if (q4 == 0) dst_s[el] = ei[2 * e + 1];

    float s1, c1;
    sincosf(phi_arr[e], &s1, &c1);
    const float c2 = c1 * c1 - s1 * s1;
    const float s2 = 2.0f * c1 * s1;

    float xt[20];
    const float4* xp = (const float4*)(xin + (size_t)src * CQ + 20 * q4);
    #pragma unroll
    for (int k4 = 0; k4 < 5; ++k4) {
        float4 v = xp[k4];
        xt[4 * k4 + 0] = v.x; xt[4 * k4 + 1] = v.y;
        xt[4 * k4 + 2] = v.z; xt[4 * k4 + 3] = v.w;
    }
    #pragma unroll
    for (int cc = 0; cc < 4; ++cc) {    // 4 channels, rotate (1,2) and (3,4)
        float a1 = xt[cc * 5 + 1], b1 = xt[cc * 5 + 2];
        float a2 = xt[cc * 5 + 3], b2 = xt[cc * 5 + 4];
        xt[cc * 5 + 1] = c1 * a1 - s1 * b1;
        xt[cc * 5 + 2] = s1 * a1 + c1 * b1;
        xt[cc * 5 + 3] = c2 * a2 - s2 * b2;
        xt[cc * 5 + 4] = s2 * a2 + c2 * b2;
    }
    float tv[NFR];
    #pragma unroll
    for (int fr = 0; fr < NFR; ++fr) tv[fr] = pre[(size_t)e * NFR + fr];

    #pragma unroll
    for (int fr = 0; fr < NFR; ++fr) {
        const float tf = tv[fr];
        uint2* dp = (uint2*)&A_s[el * AS_STRIDE + fr * CQ + 20 * q4]; // 8B-aligned
        #pragma unroll
        for (int j = 0; j < 5; ++j) {
            unsigned lo = (unsigned)f2bf(xt[4 * j + 0] * tf) |
                          ((unsigned)f2bf(xt[4 * j + 1] * tf) << 16);
            unsigned hi = (unsigned)f2bf(xt[4 * j + 2] * tf) |
                          ((unsigned)f2bf(xt[4 * j + 3] * tf) << 16);
            dp[j] = make_uint2(lo, hi);
        }
    }
    __syncthreads();

    // ---- Phase 2: GEMM ----
    const int wave = tid >> 6;          // 0..1 -> m-tile
    const int lane = tid & 63;
    const int lrow = lane & 15;
    const int quad = lane >> 4;
    const int m0 = 16 * wave;

    f32x4 acc[5];
    #pragma unroll
    for (int nt = 0; nt < 5; ++nt) acc[nt] = (f32x4){0.f, 0.f, 0.f, 0.f};

    const unsigned short* As_row = &A_s[(m0 + lrow) * AS_STRIDE];
    #pragma unroll 1
    for (int ks = 0; ks < 25; ++ks) {
        bf16x8 a = *(const bf16x8*)(As_row + 32 * ks + 8 * quad);
        #pragma unroll
        for (int nt = 0; nt < 5; ++nt) {
            bf16x8 b = *(const bf16x8*)(Wt + (size_t)(16 * nt + lrow) * KTOT
                                           + 32 * ks + 8 * quad);
            acc[nt] = __builtin_amdgcn_mfma_f32_16x16x32_bf16(a, b, acc[nt], 0, 0, 0);
        }
    }

    // ---- Phase 3: scatter ----
    #pragma unroll
    for (int nt = 0; nt < 5; ++nt) {
        #pragma unroll
        for (int r = 0; r < 4; ++r) {
            int erow = m0 + quad * 4 + r;          // local edge row
            int op = 16 * nt + lrow;
            atomicAdd(y + (size_t)dst_s[erow] * OP + op, acc[nt][r]);
        }
    }
}

// ---------------------------------------------------------------------------
// Regular nonlinearity (+ optional residual). One thread per (n,c).
// ---------------------------------------------------------------------------
__global__ void nonlin(const float* __restrict__ yin, const float* __restrict__ res,
                       float* __restrict__ out) {
    int idx = blockIdx.x * blockDim.x + threadIdx.x;  // over N*C
    if (idx >= NN * NC) return;
    const float* vp = yin + (long long)idx * NQ;
    float a0 = vp[0], a1 = vp[1], a2 = vp[2], a3 = vp[3], a4 = vp[4];
    if (res != nullptr) {
        const float* rp = res + (long long)idx * NQ;
        a0 += rp[0]; a1 += rp[1]; a2 += rp[2]; a3 += rp[3]; a4 += rp[4];
    }
    float o0 = 0.f, o1 = 0.f, o2 = 0.f, o3 = 0.f, o4 = 0.f;
    #pragma unroll
    for (int k = 0; k < 7; ++k) {
        float th = (float)(2.0 * M_PI / 7.0) * (float)k;
        float c1k = cosf(th), s1k = sinf(th);
        float c2k = cosf(2.0f * th), s2k = sinf(2.0f * th);
        float s = a0 + a1 * c1k + a2 * s1k + a3 * c2k + a4 * s2k;
        s = fmaxf(s, 0.0f);
        o0 += s;
        o1 += s * c1k; o2 += s * s1k;
        o3 += s * c2k; o4 += s * s2k;
    }
    const float i7 = 1.0f / 7.0f, t7 = 2.0f / 7.0f;
    float* op = out + (long long)idx * NQ;
    op[0] = o0 * i7;
    op[1] = o1 * t7; op[2] = o2 * t7;
    op[3] = o3 * t7; op[4] = o4 * t7;
}

// ---------------------------------------------------------------------------
extern "C" void kernel_launch(void* const* d_in, const int* in_sizes, int n_in,
                              void* d_out, int out_size, void* d_ws, size_t ws_size,
                              hipStream_t stream) {
    const float* x    = (const float*)d_in[0];
    const int*   ei   = (const int*)d_in[1];      // int inputs arrive as int32
    const float* pre  = (const float*)d_in[2];
    const float* phi  = (const float*)d_in[3];
    const float* W1   = (const float*)d_in[4];
    const float* b1   = (const float*)d_in[5];
    const float* Ws1  = (const float*)d_in[6];
    const float* W2   = (const float*)d_in[7];
    const float* b2   = (const float*)d_in[8];
    const float* Ws2  = (const float*)d_in[9];
    float* out = (float*)d_out;

    // Workspace layout
    unsigned short* Wt1 = (unsigned short*)d_ws;          // 64000 bf16 = 128 KB
    unsigned short* Wt2 = Wt1 + WSZ;                      // 128 KB
    float* y1 = (float*)(Wt2 + WSZ);                      // 800000 f (3.2 MB)
    float* h  = y1 + (size_t)NN * OP;                     // 800000 f (3.2 MB)

    reorder_wt<<<(WSZ + 255) / 256, 256, 0, stream>>>(W1, W2, Wt1, Wt2);

    // Layer 1
    selfint<<<(NN * OP + 255) / 256, 256, 0, stream>>>(x, Ws1, b1, y1);
    edge_conv_mfma<<<NE / MT, 128, 0, stream>>>(x, ei, pre, phi, Wt1, y1);
    nonlin<<<(NN * NC + 255) / 256, 256, 0, stream>>>(y1, nullptr, h);

    // Layer 2 (reuse y1)
    selfint<<<(NN * OP + 255) / 256, 256, 0, stream>>>(h, Ws2, b2, y1);
    edge_conv_mfma<<<NE / MT, 128, 0, stream>>>(h, ei, pre, phi, Wt2, y1);

    // Residual + final nonlinearity -> d_out
    nonlin<<<(NN * NC + 255) / 256, 256, 0, stream>>>(y1, x, out);
}